// Round 4
// baseline (118.389 us; speedup 1.0000x reference)
//
#include <hip/hip_runtime.h>

#define NUM_CLASSES 100000
#define FEAT_DIM    256
#define BATCH       16384
#define ALPHA       0.5f
#define EPS_        1e-6f

typedef float f4 __attribute__((ext_vector_type(4)));
typedef f4 __attribute__((aligned(4))) f4_u;   // dest out+1 is only 4B-aligned

// --- ws layout (bytes) ---
// Zeroed range: [0, OFF_ZERO_END) = counts + nslots + pad + sums (contiguous)
#define OFF_COUNTS    0u                          // 100000 * 4 = 400000
#define OFF_NSLOTS    400000u                     // 4
#define OFF_SUMS      400016u                     // 16B aligned; 16384*256*4 = 16777216
#define OFF_ZERO_END  (400016u + 16777216u)       // 17177232 (divisible by 16)
// Not zeroed (fully overwritten or bounded by nslots):
#define OFF_SLOT      OFF_ZERO_END                // 100000 * 4 = 400000
#define OFF_PART      (OFF_SLOT + 400000u)        // 16384 * 4
#define OFF_PART2     (OFF_PART + 65536u)         // 16384 * 4

// K0: vectorized zero of the contiguous [counts|nslots|sums] range.
// (hipMemsetAsync's fillBufferAligned costs ~60us fixed inside the graph — never use it.)
__global__ void zero_kernel(f4* __restrict__ p, int n) {
    int i = blockIdx.x * blockDim.x + threadIdx.x;
    if (i < n) p[i] = (f4){0.f, 0.f, 0.f, 0.f};
}

// K1: histogram + compact slot assignment (owner = thread whose add returns 0)
__global__ void count_slot_kernel(const int* __restrict__ target,
                                  int* __restrict__ counts,
                                  int* __restrict__ slot_of,
                                  int* __restrict__ nslots) {
    int i = blockIdx.x * blockDim.x + threadIdx.x;
    if (i < BATCH) {
        int t = target[i];
        int old = atomicAdd(&counts[t], 1);
        if (old == 0) slot_of[t] = atomicAdd(nslots, 1);
    }
}

// K2: wave per sample. Scatter-add features into per-class sums; store ||f||^2.
__global__ void accum_kernel(const float* __restrict__ features,
                             const int*   __restrict__ target,
                             const int*   __restrict__ slot_of,
                             float*       __restrict__ sums,
                             float*       __restrict__ partials) {
    const int wave = threadIdx.x >> 6;
    const int lane = threadIdx.x & 63;
    const int i = blockIdx.x * 4 + wave;          // BATCH % 4 == 0
    const int slot = slot_of[target[i]];          // wave-uniform

    const f4 f = *(const f4*)(features + (size_t)i * FEAT_DIM + lane * 4);
    float* s = sums + (size_t)slot * FEAT_DIM + lane * 4;
    atomicAdd(&s[0], f.x);
    atomicAdd(&s[1], f.y);
    atomicAdd(&s[2], f.z);
    atomicAdd(&s[3], f.w);

    float sq = f.x*f.x + f.y*f.y + f.z*f.z + f.w*f.w;
    #pragma unroll
    for (int off = 32; off > 0; off >>= 1)
        sq += __shfl_down(sq, off, 64);
    if (lane == 0) partials[i] = sq;              // plain store — no hot atomic
}

// K3: wave per class row. new_c = c - alpha*(cnt*c - sum_f)/(cnt+eps); loss partial.
__global__ void rewrite_kernel(const float* __restrict__ centers,
                               const int*   __restrict__ counts,
                               const int*   __restrict__ slot_of,
                               const float* __restrict__ sums,
                               float*       __restrict__ out_centers,  // d_out + 1
                               float*       __restrict__ partials2) {
    const int wave = threadIdx.x >> 6;
    const int lane = threadIdx.x & 63;
    const int row = blockIdx.x * 4 + wave;        // NUM_CLASSES % 4 == 0
    if (row >= NUM_CLASSES) return;

    const f4 c = *(const f4*)(centers + (size_t)row * FEAT_DIM + lane * 4);
    const int cnt = counts[row];                  // wave-uniform
    f4_u* dst = (f4_u*)(out_centers + (size_t)row * FEAT_DIM + lane * 4);

    if (cnt == 0) {                               // untouched: pure copy (~85% of rows)
        *dst = c;
        return;
    }
    const int slot = slot_of[row];
    const f4 sf = *(const f4*)(sums + (size_t)slot * FEAT_DIM + lane * 4);
    const float fc  = (float)cnt;
    const float inv = ALPHA / (fc + EPS_);
    f4 o;
    o.x = c.x - inv * (fc * c.x - sf.x);
    o.y = c.y - inv * (fc * c.y - sf.y);
    o.z = c.z - inv * (fc * c.z - sf.z);
    o.w = c.w - inv * (fc * c.w - sf.w);
    *dst = o;

    // loss partial for this class: cnt*||c||^2 - 2*c.sum_f  (wave-uniform branch)
    float red = fc * (c.x*c.x + c.y*c.y + c.z*c.z + c.w*c.w)
              - 2.0f * (c.x*sf.x + c.y*sf.y + c.z*sf.z + c.w*sf.w);
    #pragma unroll
    for (int off = 32; off > 0; off >>= 1)
        red += __shfl_down(red, off, 64);
    if (lane == 0) partials2[slot] = red;         // plain store
}

// K4: loss = (sum ||f||^2 + sum used class partials) / (B*D)
__global__ void reduce_loss(const float* __restrict__ partials,
                            const float* __restrict__ partials2,
                            const int*   __restrict__ nslots,
                            float* __restrict__ out) {
    const int ns = *nslots;
    float s = 0.0f;
    for (int i = threadIdx.x; i < BATCH; i += 1024) s += partials[i];
    for (int i = threadIdx.x; i < ns;    i += 1024) s += partials2[i];
    #pragma unroll
    for (int off = 32; off > 0; off >>= 1)
        s += __shfl_down(s, off, 64);
    __shared__ float wsum[16];
    const int lane = threadIdx.x & 63;
    const int wid  = threadIdx.x >> 6;
    if (lane == 0) wsum[wid] = s;
    __syncthreads();
    if (threadIdx.x == 0) {
        float tot = 0.0f;
        #pragma unroll
        for (int k = 0; k < 16; ++k) tot += wsum[k];
        out[0] = tot * (1.0f / ((float)BATCH * (float)FEAT_DIM));
    }
}

extern "C" void kernel_launch(void* const* d_in, const int* in_sizes, int n_in,
                              void* d_out, int out_size, void* d_ws, size_t ws_size,
                              hipStream_t stream) {
    const float* centers  = (const float*)d_in[0];
    const float* features = (const float*)d_in[1];
    const int*   target   = (const int*)d_in[2];

    float* out         = (float*)d_out;
    float* out_centers = out + 1;

    char* ws = (char*)d_ws;
    int*   counts   = (int*)(ws + OFF_COUNTS);
    int*   nslots   = (int*)(ws + OFF_NSLOTS);
    float* sums     = (float*)(ws + OFF_SUMS);
    int*   slot_of  = (int*)(ws + OFF_SLOT);
    float* partials = (float*)(ws + OFF_PART);
    float* partials2= (float*)(ws + OFF_PART2);

    // custom zero of counts+nslots+sums (17.2 MB) — one f4 per thread
    const int nzero = (int)(OFF_ZERO_END / 16u);
    zero_kernel<<<(nzero + 255) / 256, 256, 0, stream>>>((f4*)ws, nzero);

    count_slot_kernel<<<(BATCH + 255) / 256, 256, 0, stream>>>(target, counts, slot_of, nslots);

    accum_kernel<<<BATCH / 4, 256, 0, stream>>>(features, target, slot_of, sums, partials);

    rewrite_kernel<<<NUM_CLASSES / 4, 256, 0, stream>>>(centers, counts, slot_of, sums,
                                                        out_centers, partials2);

    reduce_loss<<<1, 1024, 0, stream>>>(partials, partials2, nslots, out);
}

// Round 5
// 54.965 us; speedup vs baseline: 2.1539x; 2.1539x over previous
//
#include <hip/hip_runtime.h>

#define NUM_CLASSES 100000
#define FEAT_DIM    256
#define BATCH       16384
#define ALPHA       0.5f
#define EPS_        1e-6f

typedef float f4 __attribute__((ext_vector_type(4)));
typedef f4 __attribute__((aligned(4))) f4_u;   // dest out+1 is only 4B-aligned

// --- ws layout (bytes) ---
// Zeroed range: counts + head + nslots (contiguous, 800016 B)
#define OFF_COUNTS    0u                          // 100000 * 4 = 400000
#define OFF_HEAD      400000u                     // 100000 * 4 (sample_idx+1; 0 = empty)
#define OFF_NSLOTS    800000u                     // 4 (+12 pad)
#define OFF_ZERO_END  800016u                     // divisible by 16
// Not zeroed (written-before-read every call):
#define OFF_SLOT      OFF_ZERO_END                // 100000 * 4 slot_of
#define OFF_NEXT      (OFF_SLOT + 400000u)        // 16384 * 4 chain links
#define OFF_PART2     (OFF_NEXT + 65536u)         // 16384 * 4 per-slot loss partials

// K0: custom zero (hipMemsetAsync's fillBuffer costs ~60us fixed in-graph — never use it)
__global__ void zero_kernel(f4* __restrict__ p, int n) {
    int i = blockIdx.x * blockDim.x + threadIdx.x;
    if (i < n) p[i] = (f4){0.f, 0.f, 0.f, 0.f};
}

// K1: histogram + compact slot assignment + per-class linked chain of samples.
// Only int atomics (16K add + 16K exch) — no bulk f32 atomics anywhere.
__global__ void count_slot_kernel(const int* __restrict__ target,
                                  int* __restrict__ counts,
                                  int* __restrict__ head,
                                  int* __restrict__ next,
                                  int* __restrict__ slot_of,
                                  int* __restrict__ nslots) {
    int i = blockIdx.x * blockDim.x + threadIdx.x;
    if (i < BATCH) {
        int t = target[i];
        int old = atomicAdd(&counts[t], 1);
        if (old == 0) slot_of[t] = atomicAdd(nslots, 1);
        int prev = atomicExch(&head[t], i + 1);   // push sample onto class chain
        next[i] = prev;
    }
}

// K2: wave per class row. Untouched rows: pure copy. Touched rows: walk the
// sample chain, gather feature rows, accumulate sum_f and sum||f||^2 in regs;
// write new center + the complete per-class loss partial.
__global__ void rewrite_kernel(const float* __restrict__ centers,
                               const float* __restrict__ features,
                               const int*   __restrict__ counts,
                               const int*   __restrict__ head,
                               const int*   __restrict__ next,
                               const int*   __restrict__ slot_of,
                               float*       __restrict__ out_centers,  // d_out + 1
                               float*       __restrict__ partials2) {
    const int wave = threadIdx.x >> 6;
    const int lane = threadIdx.x & 63;
    const int row = blockIdx.x * 4 + wave;        // NUM_CLASSES % 4 == 0
    if (row >= NUM_CLASSES) return;

    const f4 c = *(const f4*)(centers + (size_t)row * FEAT_DIM + lane * 4);
    const int cnt = counts[row];                  // wave-uniform
    f4_u* dst = (f4_u*)(out_centers + (size_t)row * FEAT_DIM + lane * 4);

    if (cnt == 0) {                               // ~85% of rows: streaming copy
        *dst = c;
        return;
    }

    f4 sumf = (f4){0.f, 0.f, 0.f, 0.f};
    float s2 = 0.0f;
    for (int j = head[row]; j != 0; j = next[j - 1]) {   // avg 1.1 iters, max ~8
        const f4 f = *(const f4*)(features + (size_t)(j - 1) * FEAT_DIM + lane * 4);
        sumf.x += f.x; sumf.y += f.y; sumf.z += f.z; sumf.w += f.w;
        s2 += f.x*f.x + f.y*f.y + f.z*f.z + f.w*f.w;
    }

    const float fc  = (float)cnt;
    const float inv = ALPHA / (fc + EPS_);
    f4 o;
    o.x = c.x - inv * (fc * c.x - sumf.x);
    o.y = c.y - inv * (fc * c.y - sumf.y);
    o.z = c.z - inv * (fc * c.z - sumf.z);
    o.w = c.w - inv * (fc * c.w - sumf.w);
    *dst = o;

    // complete loss partial for this class: sum||f||^2 + cnt*||c||^2 - 2*c.sum_f
    float red = s2
              + fc * (c.x*c.x + c.y*c.y + c.z*c.z + c.w*c.w)
              - 2.0f * (c.x*sumf.x + c.y*sumf.y + c.z*sumf.z + c.w*sumf.w);
    #pragma unroll
    for (int off = 32; off > 0; off >>= 1)
        red += __shfl_down(red, off, 64);
    if (lane == 0) partials2[slot_of[row]] = red; // compact plain store
}

// K3: loss = sum of per-class partials / (B*D). ns <= 16384 -> 64KB read, 1 block.
__global__ void reduce_loss(const float* __restrict__ partials2,
                            const int*   __restrict__ nslots,
                            float* __restrict__ out) {
    const int ns = *nslots;
    float s = 0.0f;
    for (int i = threadIdx.x; i < ns; i += 1024) s += partials2[i];
    #pragma unroll
    for (int off = 32; off > 0; off >>= 1)
        s += __shfl_down(s, off, 64);
    __shared__ float wsum[16];
    const int lane = threadIdx.x & 63;
    const int wid  = threadIdx.x >> 6;
    if (lane == 0) wsum[wid] = s;
    __syncthreads();
    if (threadIdx.x == 0) {
        float tot = 0.0f;
        #pragma unroll
        for (int k = 0; k < 16; ++k) tot += wsum[k];
        out[0] = tot * (1.0f / ((float)BATCH * (float)FEAT_DIM));
    }
}

extern "C" void kernel_launch(void* const* d_in, const int* in_sizes, int n_in,
                              void* d_out, int out_size, void* d_ws, size_t ws_size,
                              hipStream_t stream) {
    const float* centers  = (const float*)d_in[0];
    const float* features = (const float*)d_in[1];
    const int*   target   = (const int*)d_in[2];

    float* out         = (float*)d_out;
    float* out_centers = out + 1;

    char* ws = (char*)d_ws;
    int*   counts    = (int*)(ws + OFF_COUNTS);
    int*   head      = (int*)(ws + OFF_HEAD);
    int*   nslots    = (int*)(ws + OFF_NSLOTS);
    int*   slot_of   = (int*)(ws + OFF_SLOT);
    int*   next      = (int*)(ws + OFF_NEXT);
    float* partials2 = (float*)(ws + OFF_PART2);

    const int nzero = (int)(OFF_ZERO_END / 16u);  // counts + head + nslots
    zero_kernel<<<(nzero + 255) / 256, 256, 0, stream>>>((f4*)ws, nzero);

    count_slot_kernel<<<(BATCH + 255) / 256, 256, 0, stream>>>(target, counts, head, next,
                                                               slot_of, nslots);

    rewrite_kernel<<<NUM_CLASSES / 4, 256, 0, stream>>>(centers, features, counts, head,
                                                        next, slot_of, out_centers, partials2);

    reduce_loss<<<1, 1024, 0, stream>>>(partials2, nslots, out);
}